// Round 4
// baseline (137.949 us; speedup 1.0000x reference)
//
#include <hip/hip_runtime.h>
#include <hip/hip_bf16.h>
#include <cstddef>

// Problem constants
#define B_ROWS 16384
#define SDIM 512
#define ADIM 64
#define KDIM 576    // SDIM + ADIM = 9 K-tiles of 64 (exact, no pad)
#define HID 1024
#define NQ 64

typedef __attribute__((ext_vector_type(8))) __bf16 bf16x8;
typedef __attribute__((ext_vector_type(4))) float f32x4;

static __device__ __forceinline__ float bf2f(unsigned short u) {
  union { unsigned int i; float f; } x; x.i = ((unsigned int)u) << 16; return x.f;
}
static __device__ __forceinline__ unsigned short f2bf(float f) {
  union { float f; unsigned int i; } x; x.f = f;
  unsigned int i = x.i + (0x7fffu + ((x.i >> 16) & 1u)); // RNE
  return (unsigned short)(i >> 16);
}

static __device__ __forceinline__ void gload_lds16(const unsigned short* g, unsigned short* l) {
  __builtin_amdgcn_global_load_lds(
      (const __attribute__((address_space(1))) void*)(const void*)g,
      (__attribute__((address_space(3))) void*)(void*)l, 16, 0, 0);
}

// ---- tiny tau-embedding network: qoff[q] = (te @ Wt)[q] + bh ----
__global__ void qoff_k(const float* __restrict__ Wq1, const float* __restrict__ bq1,
                       const float* __restrict__ Wq2, const float* __restrict__ bq2,
                       const float* __restrict__ Wh, const float* __restrict__ bh,
                       float* __restrict__ qoff) {
  const int q = threadIdx.x;  // 64 threads
  const float tau = ((float)q + 0.5f) * (1.0f / (float)NQ);
  float t1[64];
#pragma unroll
  for (int k = 0; k < 64; ++k) t1[k] = fmaxf(fmaf(tau, Wq1[k], bq1[k]), 0.f);
  float acc = bh[0];
#pragma unroll 1
  for (int j = 0; j < 64; ++j) {
    float t2 = bq2[j];
#pragma unroll
    for (int k = 0; k < 64; ++k) t2 = fmaf(t1[k], Wq2[k * 64 + j], t2);
    acc = fmaf(t2, Wh[HID + j], acc);
  }
  qoff[q] = acc;
}

// ---- pack concat(state, action) -> bf16 [B_ROWS][KDIM] ----
__global__ void pack_x_k(const float* __restrict__ state, const float* __restrict__ action,
                         unsigned short* __restrict__ xb) {
  const int idx = blockIdx.x * blockDim.x + threadIdx.x; // one ushort4 group
  const int r = idx / (KDIM / 4);
  const int c = (idx - r * (KDIM / 4)) * 4;
  float4 v;
  if (c < SDIM) v = *(const float4*)(state + (size_t)r * SDIM + c);
  else          v = *(const float4*)(action + (size_t)r * ADIM + (c - SDIM));
  ushort4 o; o.x = f2bf(v.x); o.y = f2bf(v.y); o.z = f2bf(v.z); o.w = f2bf(v.w);
  *(ushort4*)(xb + (size_t)r * KDIM + c) = o;
}

// ---- transpose + cvt: W [Kin][N] f32 -> Wb [N][Kin] bf16 ----
__global__ __launch_bounds__(256) void transpose_cvt_k(
    const float* __restrict__ W, unsigned short* __restrict__ Wb, int Kin, int N) {
  __shared__ unsigned short tile[32][33];
  const int tx = threadIdx.x & 31, ty = threadIdx.x >> 5; // ty 0..7
  const int k0 = blockIdx.y * 32, n0 = blockIdx.x * 32;
#pragma unroll
  for (int i = 0; i < 32; i += 8)
    tile[ty + i][tx] = f2bf(W[(size_t)(k0 + ty + i) * N + n0 + tx]);
  __syncthreads();
#pragma unroll
  for (int i = 0; i < 32; i += 8)
    Wb[(size_t)(n0 + ty + i) * Kin + k0 + tx] = tile[tx][ty + i];
}

// ============================================================================
// 256x256 8-phase bf16 GEMM, m201-depth pipeline: C = bf16(A @ Bt^T + bias)
// A: [M][K] bf16, Bt: [N][K] bf16, C: [M][N] bf16.  NT = K/64.
// 512 threads = 8 waves (2M x 4N), per-wave output 128x64.
// LDS 128 KiB: A[d][h] at d*32768+h*16384, B[d][h] at 65536 + same.
// T2 swizzle (3-bit): LDS[row][slot] = G[row][slot ^ (row&7)], slot = 16B unit.
// Pipeline: 7-half prologue; per-phase 1 half-tile stage; vmcnt(6) at P4/P8
// (3 half-tiles / 6 loads stay in flight; issue->wait distance ~7 phases).
// B-frag reads compressed into P1/P5 so B halves are free for P2/P3 stages.
// ============================================================================
__global__ __launch_bounds__(512, 2) void gemm8_k(
    const unsigned short* __restrict__ A, const unsigned short* __restrict__ Bt,
    const float* __restrict__ bias, unsigned short* __restrict__ C,
    int N, int K, int NT) {
  extern __shared__ unsigned short sm[];
  const int tid = threadIdx.x;
  const int w = tid >> 6, l = tid & 63;

  // bijective XCD chunk swizzle (gridDim.x % 8 == 0)
  const int cpx = (int)gridDim.x >> 3;
  int bid = (int)blockIdx.x;
  bid = (bid & 7) * cpx + (bid >> 3);
  const int nb = N >> 8;
  const int m0 = (bid / nb) << 8, n0 = (bid % nb) << 8;

  // staging: lane covers linear LDS bytes w*1024 + l*16 (+8192) within a half;
  // row = w*8 + (l>>3) (+64), dest slot = l&7 -> source col-block = (l&7)^(l>>3).
  const int srow0 = w * 8 + (l >> 3);
  const int sce = ((l & 7) ^ (l >> 3)) << 3;  // source col offset in shorts

  // fragment-read constants (byte offsets)
  const int aB = (w >> 2) * 16384;                 // A slot = wave's M-half
  const int bB = 65536 + ((w & 3) >> 1) * 16384;   // B slot = wave's N-half
  const int lr = (l & 15) << 7;                    // row-within-slot * 128B
  const int bRow = (w & 1) << 13;                  // (w&1)*64 rows * 128B
  const int sl0 = (((l >> 4)) ^ (l & 7)) << 4;     // kk=0 swizzled slot bytes
  const int sl1 = (((l >> 4) | 4) ^ (l & 7)) << 4; // kk=1 swizzled slot bytes

  f32x4 acc[8][4] = {};
  bf16x8 ra[2][4], rb[2][4];

#define AF(d, mi, kk) (*(const bf16x8*)(sm + ((aB + (d)*32768 + (mi)*2048 + lr + ((kk) ? sl1 : sl0)) >> 1)))
#define BFR(d, ni, kk) (*(const bf16x8*)(sm + ((bB + (d)*32768 + bRow + (ni)*2048 + lr + ((kk) ? sl1 : sl0)) >> 1)))
#define STGA(d, h, kt) do { \
    const unsigned short* g_ = A + (size_t)(m0 + (h)*128 + srow0) * K + (kt) + sce; \
    unsigned short* l_ = sm + (((d)*32768 + (h)*16384 + w*1024) >> 1); \
    gload_lds16(g_, l_); gload_lds16(g_ + (size_t)64 * K, l_ + 4096); } while (0)
#define STGB(d, h, kt) do { \
    const unsigned short* g_ = Bt + (size_t)(n0 + (h)*128 + srow0) * K + (kt) + sce; \
    unsigned short* l_ = sm + ((65536 + (d)*32768 + (h)*16384 + w*1024) >> 1); \
    gload_lds16(g_, l_); gload_lds16(g_ + (size_t)64 * K, l_ + 4096); } while (0)
#define RDA(d, base) do { _Pragma("unroll") for (int kk = 0; kk < 2; ++kk) \
    _Pragma("unroll") for (int mi = 0; mi < 4; ++mi) ra[kk][mi] = AF(d, (base) + mi, kk); } while (0)
#define RDBALL(d) do { _Pragma("unroll") for (int kk = 0; kk < 2; ++kk) \
    _Pragma("unroll") for (int ni = 0; ni < 4; ++ni) rb[kk][ni] = BFR(d, ni, kk); } while (0)
#define MQ(MO, NO) do { _Pragma("unroll") for (int kk = 0; kk < 2; ++kk) \
    _Pragma("unroll") for (int mi = 0; mi < 4; ++mi) \
    _Pragma("unroll") for (int ni = 0; ni < 2; ++ni) \
      acc[(MO) + mi][(NO) + ni] = __builtin_amdgcn_mfma_f32_16x16x32_bf16( \
          ra[kk][mi], rb[kk][(NO) + ni], acc[(MO) + mi][(NO) + ni], 0, 0, 0); } while (0)
#define BAR() __builtin_amdgcn_s_barrier()
#define WAITLGKM() asm volatile("s_waitcnt lgkmcnt(0)" ::: "memory")
#define WAITVM(n) asm volatile("s_waitcnt vmcnt(" #n ")" ::: "memory")
#define PRIO1() __builtin_amdgcn_s_setprio(1)
#define PRIO0() __builtin_amdgcn_s_setprio(0)

  // prologue: 7 halves = t0{A0,A1,B0,B1} + t1{B0,B1,A0}; wait t0 (leave 6)
  STGA(0, 0, 0); STGA(0, 1, 0);
  STGB(0, 0, 0); STGB(0, 1, 0);
  STGB(1, 0, 64); STGB(1, 1, 64);
  STGA(1, 0, 64);
  WAITVM(6); BAR();

  for (int t = 0; t + 1 < NT; t += 2) {
    const int kt1 = (t + 1) << 6;
    const int kt2 = ((t + 2 < NT) ? (t + 2) : (NT - 1)) << 6;
    const int kt3 = ((t + 3 < NT) ? (t + 3) : (NT - 1)) << 6;
    // P1: reads A(mi0-3)+ALL B of buf0; stage A1(t+1); MFMA (0,0)
    RDA(0, 0); RDBALL(0); STGA(1, 1, kt1);
    BAR(); WAITLGKM();
    PRIO1(); MQ(0, 0); PRIO0();
    BAR();
    // P2: stage B0(t+2) (buf0 B free after P1); MFMA (0,2)
    STGB(0, 0, kt2);
    BAR();
    PRIO1(); MQ(0, 2); PRIO0();
    BAR();
    // P3: reads A(mi4-7); stage B1(t+2); MFMA (4,2)
    RDA(0, 4); STGB(0, 1, kt2);
    BAR(); WAITLGKM();
    PRIO1(); MQ(4, 2); PRIO0();
    BAR();
    // P4: stage A0(t+2) (buf0 A free after P3); MFMA (4,0); vmcnt(6) covers t+1
    STGA(0, 0, kt2);
    BAR();
    PRIO1(); MQ(4, 0); PRIO0();
    WAITVM(6); BAR();
    // P5: buf1 reads A(mi0-3)+ALL B; stage A1(t+2); MFMA (0,0)
    RDA(1, 0); RDBALL(1); STGA(0, 1, kt2);
    BAR(); WAITLGKM();
    PRIO1(); MQ(0, 0); PRIO0();
    BAR();
    // P6: stage B0(t+3); MFMA (0,2)
    STGB(1, 0, kt3);
    BAR();
    PRIO1(); MQ(0, 2); PRIO0();
    BAR();
    // P7: reads A(mi4-7); stage B1(t+3); MFMA (4,2)
    RDA(1, 4); STGB(1, 1, kt3);
    BAR(); WAITLGKM();
    PRIO1(); MQ(4, 2); PRIO0();
    BAR();
    // P8: stage A0(t+3); MFMA (4,0); vmcnt(6) covers t+2
    STGA(1, 0, kt3);
    BAR();
    PRIO1(); MQ(4, 0); PRIO0();
    WAITVM(6); BAR();
  }

  if (NT & 1) {
    // tail: tile NT-1 in buf0 (covered by last end-P8 vmcnt(6)); no stages.
    RDA(0, 0); RDBALL(0);
    WAITLGKM();
    PRIO1(); MQ(0, 0); MQ(0, 2); PRIO0();
    RDA(0, 4);
    WAITLGKM();
    PRIO1(); MQ(4, 2); MQ(4, 0); PRIO0();
  }

  // epilogue: drain stray prefetches, then C = bf16(acc + bias[col])
  WAITVM(0);
  const int wr = (w >> 2) << 7, wc = (w & 3) << 6;
#pragma unroll
  for (int mi = 0; mi < 8; ++mi) {
    const int row = m0 + wr + mi * 16 + ((l >> 4) << 2);
#pragma unroll
    for (int ni = 0; ni < 4; ++ni) {
      const int col = n0 + wc + ni * 16 + (l & 15);
      const float bc = bias[col];
#pragma unroll
      for (int r = 0; r < 4; ++r)
        C[(size_t)(row + r) * N + col] = f2bf(acc[mi][ni][r] + bc);
    }
  }
#undef AF
#undef BFR
#undef STGA
#undef STGB
#undef RDA
#undef RDBALL
#undef MQ
#undef BAR
#undef WAITLGKM
#undef WAITVM
}

// ---- LayerNorm + ReLU -> bf16, one wave per row of 1024 ----
__global__ __launch_bounds__(256) void ln_relu_k(
    const unsigned short* __restrict__ X, const float* __restrict__ g,
    const float* __restrict__ be, unsigned short* __restrict__ Y) {
  const int w = threadIdx.x >> 6, l = threadIdx.x & 63;
  const size_t row = (size_t)blockIdx.x * 4 + w;
  const unsigned short* xr = X + row * HID;
  float v[16];
  float sum = 0.f, ss = 0.f;
#pragma unroll
  for (int c = 0; c < 4; ++c) {
    ushort4 u = *(const ushort4*)(xr + (c * 64 + l) * 4);
    float a0 = bf2f(u.x), a1 = bf2f(u.y), a2 = bf2f(u.z), a3 = bf2f(u.w);
    v[c * 4 + 0] = a0; v[c * 4 + 1] = a1; v[c * 4 + 2] = a2; v[c * 4 + 3] = a3;
    sum += a0 + a1 + a2 + a3;
    ss += a0 * a0 + a1 * a1 + a2 * a2 + a3 * a3;
  }
#pragma unroll
  for (int o = 32; o > 0; o >>= 1) {
    sum += __shfl_xor(sum, o, 64);
    ss  += __shfl_xor(ss, o, 64);
  }
  const float mu = sum * (1.f / HID);
  const float rs = rsqrtf(ss * (1.f / HID) - mu * mu + 1e-5f);
  unsigned short* yr = Y + row * HID;
#pragma unroll
  for (int c = 0; c < 4; ++c) {
    const int col = (c * 64 + l) * 4;
    float4 gg = *(const float4*)(g + col);
    float4 bb = *(const float4*)(be + col);
    ushort4 o4;
    o4.x = f2bf(fmaxf((v[c * 4 + 0] - mu) * rs * gg.x + bb.x, 0.f));
    o4.y = f2bf(fmaxf((v[c * 4 + 1] - mu) * rs * gg.y + bb.y, 0.f));
    o4.z = f2bf(fmaxf((v[c * 4 + 2] - mu) * rs * gg.z + bb.z, 0.f));
    o4.w = f2bf(fmaxf((v[c * 4 + 3] - mu) * rs * gg.w + bb.w, 0.f));
    *(ushort4*)(yr + col) = o4;
  }
}

// ---- LN2 + ReLU + dot(row, Wf) + qoff broadcast -> out [B_ROWS][NQ] f32 ----
__global__ __launch_bounds__(256) void ln_final_k(
    const unsigned short* __restrict__ X, const float* __restrict__ g,
    const float* __restrict__ be, const float* __restrict__ Wh,
    const float* __restrict__ qoff, float* __restrict__ out) {
  const int w = threadIdx.x >> 6, l = threadIdx.x & 63;
  const size_t row = (size_t)blockIdx.x * 4 + w;
  const unsigned short* xr = X + row * HID;
  float v[16];
  float sum = 0.f, ss = 0.f;
#pragma unroll
  for (int c = 0; c < 4; ++c) {
    ushort4 u = *(const ushort4*)(xr + (c * 64 + l) * 4);
    float a0 = bf2f(u.x), a1 = bf2f(u.y), a2 = bf2f(u.z), a3 = bf2f(u.w);
    v[c * 4 + 0] = a0; v[c * 4 + 1] = a1; v[c * 4 + 2] = a2; v[c * 4 + 3] = a3;
    sum += a0 + a1 + a2 + a3;
    ss += a0 * a0 + a1 * a1 + a2 * a2 + a3 * a3;
  }
#pragma unroll
  for (int o = 32; o > 0; o >>= 1) {
    sum += __shfl_xor(sum, o, 64);
    ss  += __shfl_xor(ss, o, 64);
  }
  const float mu = sum * (1.f / HID);
  const float rs = rsqrtf(ss * (1.f / HID) - mu * mu + 1e-5f);
  float dot = 0.f;
#pragma unroll
  for (int c = 0; c < 4; ++c) {
    const int col = (c * 64 + l) * 4;
    float4 gg = *(const float4*)(g + col);
    float4 bb = *(const float4*)(be + col);
    float4 wf = *(const float4*)(Wh + col); // Wf = Wh[:HID]
    dot += fmaxf((v[c * 4 + 0] - mu) * rs * gg.x + bb.x, 0.f) * wf.x;
    dot += fmaxf((v[c * 4 + 1] - mu) * rs * gg.y + bb.y, 0.f) * wf.y;
    dot += fmaxf((v[c * 4 + 2] - mu) * rs * gg.z + bb.z, 0.f) * wf.z;
    dot += fmaxf((v[c * 4 + 3] - mu) * rs * gg.w + bb.w, 0.f) * wf.w;
  }
#pragma unroll
  for (int o = 32; o > 0; o >>= 1) dot += __shfl_xor(dot, o, 64);
  out[row * NQ + l] = dot + qoff[l];
}

extern "C" void kernel_launch(void* const* d_in, const int* in_sizes, int n_in,
                              void* d_out, int out_size, void* d_ws, size_t ws_size,
                              hipStream_t stream) {
  const float* state  = (const float*)d_in[0];
  const float* action = (const float*)d_in[1];
  const float* W1  = (const float*)d_in[2];
  const float* b1  = (const float*)d_in[3];
  const float* g1  = (const float*)d_in[4];
  const float* be1 = (const float*)d_in[5];
  const float* W2  = (const float*)d_in[6];
  const float* b2  = (const float*)d_in[7];
  const float* g2  = (const float*)d_in[8];
  const float* be2 = (const float*)d_in[9];
  const float* Wq1 = (const float*)d_in[10];
  const float* bq1 = (const float*)d_in[11];
  const float* Wq2 = (const float*)d_in[12];
  const float* bq2 = (const float*)d_in[13];
  const float* Wh  = (const float*)d_in[14];
  const float* bh  = (const float*)d_in[15];
  float* out = (float*)d_out;

  // workspace layout (~90 MB)
  char* ws = (char*)d_ws;
  size_t off = 0;
  float* qoff = (float*)(ws + off); off += 256;
  unsigned short* xb  = (unsigned short*)(ws + off); off += (size_t)B_ROWS * KDIM * 2; // 18.87 MB
  unsigned short* w1b = (unsigned short*)(ws + off); off += (size_t)HID * KDIM * 2;    // 1.18 MB
  unsigned short* w2b = (unsigned short*)(ws + off); off += (size_t)HID * HID * 2;     // 2.10 MB
  unsigned short* h1b = (unsigned short*)(ws + off); off += (size_t)B_ROWS * HID * 2;  // 33.55 MB
  unsigned short* tb  = (unsigned short*)(ws + off);                                   // 33.55 MB

  hipFuncSetAttribute((const void*)gemm8_k, hipFuncAttributeMaxDynamicSharedMemorySize, 131072);

  qoff_k<<<1, 64, 0, stream>>>(Wq1, bq1, Wq2, bq2, Wh, bh, qoff);
  pack_x_k<<<(B_ROWS * (KDIM / 4)) / 256, 256, 0, stream>>>(state, action, xb);
  transpose_cvt_k<<<dim3(HID / 32, KDIM / 32), 256, 0, stream>>>(W1, w1b, KDIM, HID);
  transpose_cvt_k<<<dim3(HID / 32, HID / 32), 256, 0, stream>>>(W2, w2b, HID, HID);

  gemm8_k<<<(B_ROWS / 256) * (HID / 256), 512, 131072, stream>>>(xb, w1b, b1, tb, HID, KDIM, KDIM / 64);
  ln_relu_k<<<B_ROWS / 4, 256, 0, stream>>>(tb, g1, be1, h1b);
  gemm8_k<<<(B_ROWS / 256) * (HID / 256), 512, 131072, stream>>>(h1b, w2b, b2, tb, HID, HID, HID / 64);
  ln_final_k<<<B_ROWS / 4, 256, 0, stream>>>(tb, g2, be2, Wh, qoff, out);
}

// Round 5
// 123.774 us; speedup vs baseline: 1.1145x; 1.1145x over previous
//
#include <hip/hip_runtime.h>
#include <hip/hip_bf16.h>
#include <cstddef>

// Problem constants
#define B_ROWS 16384
#define SDIM 512
#define ADIM 64
#define KDIM 576    // SDIM + ADIM
#define KPAD1 640   // KDIM padded to 10 K-tiles of 64
#define HID 1024
#define NQ 64

// prep-kernel block ranges
#define PACK_BLOCKS 10240            // B_ROWS*(KPAD1/4)/256
#define T1_BLOCKS 640                // (HID/32)*(KPAD1/32)
#define T2_BLOCKS 1024               // (HID/32)*(HID/32)
#define PREP_BLOCKS (PACK_BLOCKS + T1_BLOCKS + T2_BLOCKS + 1)

typedef __attribute__((ext_vector_type(8))) __bf16 bf16x8;
typedef __attribute__((ext_vector_type(4))) float f32x4;

static __device__ __forceinline__ float bf2f(unsigned short u) {
  union { unsigned int i; float f; } x; x.i = ((unsigned int)u) << 16; return x.f;
}
static __device__ __forceinline__ unsigned short f2bf(float f) {
  union { float f; unsigned int i; } x; x.f = f;
  unsigned int i = x.i + (0x7fffu + ((x.i >> 16) & 1u)); // RNE
  return (unsigned short)(i >> 16);
}

static __device__ __forceinline__ void gload_lds16(const unsigned short* g, unsigned short* l) {
  __builtin_amdgcn_global_load_lds(
      (const __attribute__((address_space(1))) void*)(const void*)g,
      (__attribute__((address_space(3))) void*)(void*)l, 16, 0, 0);
}

// ---- transpose helper: W [Kin][N] f32 -> Wb [N][Kpad] bf16 (zero pad) ----
static __device__ __forceinline__ void transpose_body(
    const float* __restrict__ W, unsigned short* __restrict__ Wb,
    int Kin, int Kpad, int N, int k0, int n0, unsigned short* tile /* [32][33] */) {
  const int tx = threadIdx.x & 31, ty = threadIdx.x >> 5; // ty 0..7
#pragma unroll
  for (int i = 0; i < 32; i += 8) {
    const int k = k0 + ty + i;
    tile[(ty + i) * 33 + tx] = (k < Kin) ? f2bf(W[(size_t)k * N + n0 + tx]) : (unsigned short)0;
  }
  __syncthreads();
#pragma unroll
  for (int i = 0; i < 32; i += 8)
    Wb[(size_t)(n0 + ty + i) * Kpad + k0 + tx] = tile[tx * 33 + ty + i];
}

// ---- fused prep: pack_x + transpose(W1) + transpose(W2) + qoff, one dispatch ----
__global__ __launch_bounds__(256) void prep_k(
    const float* __restrict__ state, const float* __restrict__ action,
    const float* __restrict__ W1, const float* __restrict__ W2,
    const float* __restrict__ Wq1, const float* __restrict__ bq1,
    const float* __restrict__ Wq2, const float* __restrict__ bq2,
    const float* __restrict__ Wh, const float* __restrict__ bh,
    unsigned short* __restrict__ xb, unsigned short* __restrict__ w1b,
    unsigned short* __restrict__ w2b, float* __restrict__ qoff) {
  __shared__ unsigned short tile[32 * 33];
  const int b = blockIdx.x;
  if (b < PACK_BLOCKS) {
    // pack concat(state, action) -> bf16 [B_ROWS][KPAD1], zero pad
    const int idx = b * 256 + threadIdx.x;
    const int r = idx / (KPAD1 / 4);
    const int c = (idx - r * (KPAD1 / 4)) * 4;
    ushort4 o;
    if (c < SDIM) {
      float4 v = *(const float4*)(state + (size_t)r * SDIM + c);
      o.x = f2bf(v.x); o.y = f2bf(v.y); o.z = f2bf(v.z); o.w = f2bf(v.w);
    } else if (c < KDIM) {
      float4 v = *(const float4*)(action + (size_t)r * ADIM + (c - SDIM));
      o.x = f2bf(v.x); o.y = f2bf(v.y); o.z = f2bf(v.z); o.w = f2bf(v.w);
    } else {
      o.x = 0; o.y = 0; o.z = 0; o.w = 0;
    }
    *(ushort4*)(xb + (size_t)r * KPAD1 + c) = o;
  } else if (b < PACK_BLOCKS + T1_BLOCKS) {
    const int t = b - PACK_BLOCKS;
    transpose_body(W1, w1b, KDIM, KPAD1, HID, (t / 32) * 32, (t % 32) * 32, tile);
  } else if (b < PACK_BLOCKS + T1_BLOCKS + T2_BLOCKS) {
    const int t = b - PACK_BLOCKS - T1_BLOCKS;
    transpose_body(W2, w2b, HID, HID, HID, (t / 32) * 32, (t % 32) * 32, tile);
  } else {
    // qoff[q] = (te @ Wt)[q] + bh  (64 threads active)
    const int q = threadIdx.x;
    if (q < NQ) {
      const float tau = ((float)q + 0.5f) * (1.0f / (float)NQ);
      float t1[64];
#pragma unroll
      for (int k = 0; k < 64; ++k) t1[k] = fmaxf(fmaf(tau, Wq1[k], bq1[k]), 0.f);
      float acc = bh[0];
#pragma unroll 1
      for (int j = 0; j < 64; ++j) {
        float t2 = bq2[j];
#pragma unroll
        for (int k = 0; k < 64; ++k) t2 = fmaf(t1[k], Wq2[k * 64 + j], t2);
        acc = fmaf(t2, Wh[HID + j], acc);
      }
      qoff[q] = acc;
    }
  }
}

// ============================================================================
// 256x256 8-phase bf16 GEMM (round-2 configuration, best measured):
// C = bf16(A @ Bt^T + bias).  A: [M][K] bf16, Bt: [N][K] bf16, K % 128 == 0.
// 512 threads = 8 waves (2M x 4N), per-wave output 128x64.
// LDS 128 KiB: A[d][h] at d*32768+h*16384, B[d][h] at 65536 + same.
// st_16x32 swizzle (m201's): byte ^= ((byte>>9)&1)<<5, inverse on global src.
// vmcnt(4) at P4/P8; optional lgkmcnt(8) partial drain in 12-read phases.
// ============================================================================
__global__ __launch_bounds__(512, 2) void gemm8_k(
    const unsigned short* __restrict__ A, const unsigned short* __restrict__ Bt,
    const float* __restrict__ bias, unsigned short* __restrict__ C,
    int N, int K, int NT) {
  extern __shared__ unsigned short sm[];
  const int tid = threadIdx.x;
  const int w = tid >> 6, l = tid & 63;

  // bijective XCD chunk swizzle (gridDim.x % 8 == 0)
  const int cpx = (int)gridDim.x >> 3;
  int bid = (int)blockIdx.x;
  bid = (bid & 7) * cpx + (bid >> 3);
  const int nb = N >> 8;
  const int m0 = (bid / nb) << 8, n0 = (bid % nb) << 8;

  // staging mapping: lane covers linear LDS slot (w*1024 + l*16) within half;
  // row = i*64 + w*8 + (l>>3), col bytes = (l&7)*16, inverse-swizzled source.
  const int srow0 = w * 8 + (l >> 3);
  const int sce = ((((l & 7) << 4) ^ ((srow0 & 4) << 3)) >> 1);

  // fragment-read constants (byte offsets)
  const int aB = (w >> 2) * 16384;                 // A slot = wave's M-half
  const int bB = 65536 + ((w & 3) >> 1) * 16384;   // B slot = wave's N-half
  const int lr = (l & 15) << 7;                    // row-within-slot * 128B
  const int bRow = (w & 1) << 13;                  // (w&1)*64 rows * 128B
  const int cSw = (((l >> 4) << 4) ^ ((l & 4) << 3)); // swizzled col bytes

  f32x4 acc[8][4] = {};
  bf16x8 ra[2][4], rb[2][4];

#define AF(d, mi, kk) (*(const bf16x8*)(sm + ((aB + (d)*32768 + (mi)*2048 + lr + cSw + ((kk) << 6)) >> 1)))
#define BFR(d, ni, kk) (*(const bf16x8*)(sm + ((bB + (d)*32768 + bRow + (ni)*2048 + lr + cSw + ((kk) << 6)) >> 1)))
#define STGA(d, h, kt) do { \
    const unsigned short* g_ = A + (size_t)(m0 + (h)*128 + srow0) * K + (kt) + sce; \
    unsigned short* l_ = sm + (((d)*32768 + (h)*16384 + w*1024) >> 1); \
    gload_lds16(g_, l_); gload_lds16(g_ + (size_t)64 * K, l_ + 4096); } while (0)
#define STGB(d, h, kt) do { \
    const unsigned short* g_ = Bt + (size_t)(n0 + (h)*128 + srow0) * K + (kt) + sce; \
    unsigned short* l_ = sm + ((65536 + (d)*32768 + (h)*16384 + w*1024) >> 1); \
    gload_lds16(g_, l_); gload_lds16(g_ + (size_t)64 * K, l_ + 4096); } while (0)
#define RDA(d, base) do { _Pragma("unroll") for (int kk = 0; kk < 2; ++kk) \
    _Pragma("unroll") for (int mi = 0; mi < 4; ++mi) ra[kk][mi] = AF(d, (base) + mi, kk); } while (0)
#define RDB(d, base) do { _Pragma("unroll") for (int kk = 0; kk < 2; ++kk) \
    _Pragma("unroll") for (int ni = 0; ni < 2; ++ni) rb[kk][(base) + ni] = BFR(d, (base) + ni, kk); } while (0)
#define MQ(MO, NO) do { _Pragma("unroll") for (int kk = 0; kk < 2; ++kk) \
    _Pragma("unroll") for (int mi = 0; mi < 4; ++mi) \
    _Pragma("unroll") for (int ni = 0; ni < 2; ++ni) \
      acc[(MO) + mi][(NO) + ni] = __builtin_amdgcn_mfma_f32_16x16x32_bf16( \
          ra[kk][mi], rb[kk][(NO) + ni], acc[(MO) + mi][(NO) + ni], 0, 0, 0); } while (0)
#define BAR() __builtin_amdgcn_s_barrier()
#define WAITLGKM() asm volatile("s_waitcnt lgkmcnt(0)" ::: "memory")
#define WAITLGKM8() asm volatile("s_waitcnt lgkmcnt(8)" ::: "memory")
#define WAITVM(n) asm volatile("s_waitcnt vmcnt(" #n ")" ::: "memory")

  // prologue: tile0 fully + tile1 B-halves (12 loads); wait tile0 (leave 4)
  STGA(0, 0, 0); STGA(0, 1, 0); STGB(0, 0, 0); STGB(0, 1, 0);
  STGB(1, 0, 64); STGB(1, 1, 64);
  WAITVM(4); BAR();

  for (int t = 0; t < NT; t += 2) {
    const int kt1 = (t + 1) << 6;
    const int kt2 = ((t + 2 < NT) ? (t + 2) : (NT - 1)) << 6;
    const int kt3 = ((t + 3 < NT) ? (t + 3) : (NT - 1)) << 6;
    // P1: A(mh0)+B(nh0) reads, stage A[1][0]<-t+1, MFMA quad (0,0)
    RDA(0, 0); RDB(0, 0); STGA(1, 0, kt1);
    WAITLGKM8();
    BAR(); WAITLGKM();
    __builtin_amdgcn_s_setprio(1); MQ(0, 0); __builtin_amdgcn_s_setprio(0);
    BAR();
    // P2: B(nh1) reads, stage A[1][1]<-t+1, MFMA (0,2)
    RDB(0, 2); STGA(1, 1, kt1);
    BAR(); WAITLGKM();
    __builtin_amdgcn_s_setprio(1); MQ(0, 2); __builtin_amdgcn_s_setprio(0);
    BAR();
    // P3: A(mh1) reads, stage B[0][0]<-t+2 (B[0] last read in P2), MFMA (4,2)
    RDA(0, 4); STGB(0, 0, kt2);
    BAR(); WAITLGKM();
    __builtin_amdgcn_s_setprio(1); MQ(4, 2); __builtin_amdgcn_s_setprio(0);
    BAR();
    // P4: stage B[0][1]<-t+2, MFMA (4,0); counted wait: tile t+1 landed
    STGB(0, 1, kt2);
    BAR();
    __builtin_amdgcn_s_setprio(1); MQ(4, 0); __builtin_amdgcn_s_setprio(0);
    WAITVM(4); BAR();
    // P5: buf1 A(mh0)+B(nh0), stage A[0][0]<-t+2 (A[0] last read in P3), MFMA (0,0)
    RDA(1, 0); RDB(1, 0); STGA(0, 0, kt2);
    WAITLGKM8();
    BAR(); WAITLGKM();
    __builtin_amdgcn_s_setprio(1); MQ(0, 0); __builtin_amdgcn_s_setprio(0);
    BAR();
    // P6: B(nh1), stage A[0][1]<-t+2, MFMA (0,2)
    RDB(1, 2); STGA(0, 1, kt2);
    BAR(); WAITLGKM();
    __builtin_amdgcn_s_setprio(1); MQ(0, 2); __builtin_amdgcn_s_setprio(0);
    BAR();
    // P7: A(mh1), stage B[1][0]<-t+3 (B[1] last read in P6), MFMA (4,2)
    RDA(1, 4); STGB(1, 0, kt3);
    BAR(); WAITLGKM();
    __builtin_amdgcn_s_setprio(1); MQ(4, 2); __builtin_amdgcn_s_setprio(0);
    BAR();
    // P8: stage B[1][1]<-t+3, MFMA (4,0); counted wait: tile t+2 landed
    STGB(1, 1, kt3);
    BAR();
    __builtin_amdgcn_s_setprio(1); MQ(4, 0); __builtin_amdgcn_s_setprio(0);
    WAITVM(4); BAR();
  }

  // epilogue: drain staging queue, then C = bf16(acc + bias[col])
  WAITVM(0);
  const int wr = (w >> 2) << 7, wc = (w & 3) << 6;
#pragma unroll
  for (int mi = 0; mi < 8; ++mi) {
    const int row = m0 + wr + mi * 16 + ((l >> 4) << 2);
#pragma unroll
    for (int ni = 0; ni < 4; ++ni) {
      const int col = n0 + wc + ni * 16 + (l & 15);
      const float bc = bias[col];
#pragma unroll
      for (int r = 0; r < 4; ++r)
        C[(size_t)(row + r) * N + col] = f2bf(acc[mi][ni][r] + bc);
    }
  }
#undef AF
#undef BFR
#undef STGA
#undef STGB
#undef RDA
#undef RDB
#undef MQ
#undef BAR
#undef WAITLGKM
#undef WAITLGKM8
#undef WAITVM
}

// ---- LayerNorm + ReLU -> bf16, one wave per row of 1024 ----
__global__ __launch_bounds__(256) void ln_relu_k(
    const unsigned short* __restrict__ X, const float* __restrict__ g,
    const float* __restrict__ be, unsigned short* __restrict__ Y) {
  const int w = threadIdx.x >> 6, l = threadIdx.x & 63;
  const size_t row = (size_t)blockIdx.x * 4 + w;
  const unsigned short* xr = X + row * HID;
  float v[16];
  float sum = 0.f, ss = 0.f;
#pragma unroll
  for (int c = 0; c < 4; ++c) {
    ushort4 u = *(const ushort4*)(xr + (c * 64 + l) * 4);
    float a0 = bf2f(u.x), a1 = bf2f(u.y), a2 = bf2f(u.z), a3 = bf2f(u.w);
    v[c * 4 + 0] = a0; v[c * 4 + 1] = a1; v[c * 4 + 2] = a2; v[c * 4 + 3] = a3;
    sum += a0 + a1 + a2 + a3;
    ss += a0 * a0 + a1 * a1 + a2 * a2 + a3 * a3;
  }
#pragma unroll
  for (int o = 32; o > 0; o >>= 1) {
    sum += __shfl_xor(sum, o, 64);
    ss  += __shfl_xor(ss, o, 64);
  }
  const float mu = sum * (1.f / HID);
  const float rs = rsqrtf(ss * (1.f / HID) - mu * mu + 1e-5f);
  unsigned short* yr = Y + row * HID;
#pragma unroll
  for (int c = 0; c < 4; ++c) {
    const int col = (c * 64 + l) * 4;
    float4 gg = *(const float4*)(g + col);
    float4 bb = *(const float4*)(be + col);
    ushort4 o4;
    o4.x = f2bf(fmaxf((v[c * 4 + 0] - mu) * rs * gg.x + bb.x, 0.f));
    o4.y = f2bf(fmaxf((v[c * 4 + 1] - mu) * rs * gg.y + bb.y, 0.f));
    o4.z = f2bf(fmaxf((v[c * 4 + 2] - mu) * rs * gg.z + bb.z, 0.f));
    o4.w = f2bf(fmaxf((v[c * 4 + 3] - mu) * rs * gg.w + bb.w, 0.f));
    *(ushort4*)(yr + col) = o4;
  }
}

// ---- LN2 + ReLU + dot(row, Wf) + qoff broadcast -> out [B_ROWS][NQ] f32 ----
__global__ __launch_bounds__(256) void ln_final_k(
    const unsigned short* __restrict__ X, const float* __restrict__ g,
    const float* __restrict__ be, const float* __restrict__ Wh,
    const float* __restrict__ qoff, float* __restrict__ out) {
  const int w = threadIdx.x >> 6, l = threadIdx.x & 63;
  const size_t row = (size_t)blockIdx.x * 4 + w;
  const unsigned short* xr = X + row * HID;
  float v[16];
  float sum = 0.f, ss = 0.f;
#pragma unroll
  for (int c = 0; c < 4; ++c) {
    ushort4 u = *(const ushort4*)(xr + (c * 64 + l) * 4);
    float a0 = bf2f(u.x), a1 = bf2f(u.y), a2 = bf2f(u.z), a3 = bf2f(u.w);
    v[c * 4 + 0] = a0; v[c * 4 + 1] = a1; v[c * 4 + 2] = a2; v[c * 4 + 3] = a3;
    sum += a0 + a1 + a2 + a3;
    ss += a0 * a0 + a1 * a1 + a2 * a2 + a3 * a3;
  }
#pragma unroll
  for (int o = 32; o > 0; o >>= 1) {
    sum += __shfl_xor(sum, o, 64);
    ss  += __shfl_xor(ss, o, 64);
  }
  const float mu = sum * (1.f / HID);
  const float rs = rsqrtf(ss * (1.f / HID) - mu * mu + 1e-5f);
  float dot = 0.f;
#pragma unroll
  for (int c = 0; c < 4; ++c) {
    const int col = (c * 64 + l) * 4;
    float4 gg = *(const float4*)(g + col);
    float4 bb = *(const float4*)(be + col);
    float4 wf = *(const float4*)(Wh + col); // Wf = Wh[:HID]
    dot += fmaxf((v[c * 4 + 0] - mu) * rs * gg.x + bb.x, 0.f) * wf.x;
    dot += fmaxf((v[c * 4 + 1] - mu) * rs * gg.y + bb.y, 0.f) * wf.y;
    dot += fmaxf((v[c * 4 + 2] - mu) * rs * gg.z + bb.z, 0.f) * wf.z;
    dot += fmaxf((v[c * 4 + 3] - mu) * rs * gg.w + bb.w, 0.f) * wf.w;
  }
#pragma unroll
  for (int o = 32; o > 0; o >>= 1) dot += __shfl_xor(dot, o, 64);
  out[row * NQ + l] = dot + qoff[l];
}

extern "C" void kernel_launch(void* const* d_in, const int* in_sizes, int n_in,
                              void* d_out, int out_size, void* d_ws, size_t ws_size,
                              hipStream_t stream) {
  const float* state  = (const float*)d_in[0];
  const float* action = (const float*)d_in[1];
  const float* W1  = (const float*)d_in[2];
  const float* b1  = (const float*)d_in[3];
  const float* g1  = (const float*)d_in[4];
  const float* be1 = (const float*)d_in[5];
  const float* W2  = (const float*)d_in[6];
  const float* b2  = (const float*)d_in[7];
  const float* g2  = (const float*)d_in[8];
  const float* be2 = (const float*)d_in[9];
  const float* Wq1 = (const float*)d_in[10];
  const float* bq1 = (const float*)d_in[11];
  const float* Wq2 = (const float*)d_in[12];
  const float* bq2 = (const float*)d_in[13];
  const float* Wh  = (const float*)d_in[14];
  const float* bh  = (const float*)d_in[15];
  float* out = (float*)d_out;

  // workspace layout (~91.5 MB)
  char* ws = (char*)d_ws;
  size_t off = 0;
  float* qoff = (float*)(ws + off); off += 256;
  unsigned short* xb  = (unsigned short*)(ws + off); off += (size_t)B_ROWS * KPAD1 * 2; // 20.97 MB
  unsigned short* w1b = (unsigned short*)(ws + off); off += (size_t)HID * KPAD1 * 2;    // 1.31 MB
  unsigned short* w2b = (unsigned short*)(ws + off); off += (size_t)HID * HID * 2;      // 2.10 MB
  unsigned short* h1b = (unsigned short*)(ws + off); off += (size_t)B_ROWS * HID * 2;   // 33.55 MB
  unsigned short* tb  = (unsigned short*)(ws + off);                                    // 33.55 MB

  hipFuncSetAttribute((const void*)gemm8_k, hipFuncAttributeMaxDynamicSharedMemorySize, 131072);

  prep_k<<<PREP_BLOCKS, 256, 0, stream>>>(state, action, W1, W2, Wq1, bq1, Wq2, bq2,
                                          Wh, bh, xb, w1b, w2b, qoff);

  gemm8_k<<<(B_ROWS / 256) * (HID / 256), 512, 131072, stream>>>(xb, w1b, b1, tb, HID, KPAD1, KPAD1 / 64);
  ln_relu_k<<<B_ROWS / 4, 256, 0, stream>>>(tb, g1, be1, h1b);
  gemm8_k<<<(B_ROWS / 256) * (HID / 256), 512, 131072, stream>>>(h1b, w2b, b2, tb, HID, HID, HID / 64);
  ln_final_k<<<B_ROWS / 4, 256, 0, stream>>>(tb, g2, be2, Wh, qoff, out);
}

// Round 6
// 121.145 us; speedup vs baseline: 1.1387x; 1.0217x over previous
//
#include <hip/hip_runtime.h>
#include <hip/hip_bf16.h>
#include <cstddef>

// Problem constants
#define B_ROWS 16384
#define SDIM 512
#define ADIM 64
#define KDIM 576    // SDIM + ADIM
#define KPAD1 640   // KDIM padded to 10 K-tiles of 64
#define HID 1024
#define NQ 64

// prep segmentation (8-element work items, all boundaries 64-aligned)
#define SEG0_ITEMS (B_ROWS * (SDIM / 8))               // 1,048,576 state items
#define SEG1_ITEMS (B_ROWS * (ADIM / 8))               // 131,072 action items
#define SEG2_ITEMS (B_ROWS * ((KPAD1 - KDIM) / 8))     // 131,072 zero-pad items
#define EW_ITEMS (SEG0_ITEMS + SEG1_ITEMS + SEG2_ITEMS)
#define EW_BLOCKS 2048
#define T1_BLOCKS 640                // (KPAD1/32)*(HID/32)
#define T2_BLOCKS 1024               // (HID/32)*(HID/32)
#define PREP_BLOCKS (EW_BLOCKS + T1_BLOCKS + T2_BLOCKS + 1)

typedef __attribute__((ext_vector_type(8))) __bf16 bf16x8;
typedef __attribute__((ext_vector_type(4))) float f32x4;

static __device__ __forceinline__ float bf2f(unsigned short u) {
  union { unsigned int i; float f; } x; x.i = ((unsigned int)u) << 16; return x.f;
}
static __device__ __forceinline__ unsigned short f2bf(float f) {
  union { float f; unsigned int i; } x; x.f = f;
  unsigned int i = x.i + (0x7fffu + ((x.i >> 16) & 1u)); // RNE
  return (unsigned short)(i >> 16);
}

static __device__ __forceinline__ void gload_lds16(const unsigned short* g, unsigned short* l) {
  __builtin_amdgcn_global_load_lds(
      (const __attribute__((address_space(1))) void*)(const void*)g,
      (__attribute__((address_space(3))) void*)(void*)l, 16, 0, 0);
}

static __device__ __forceinline__ ushort4 cvt8lo(float4 a) {
  ushort4 o; o.x = f2bf(a.x); o.y = f2bf(a.y); o.z = f2bf(a.z); o.w = f2bf(a.w);
  return o;
}

// ---- transpose helper: W [Kin][N] f32 -> Wb [N][Kpad] bf16 (zero pad) ----
static __device__ __forceinline__ void transpose_body(
    const float* __restrict__ W, unsigned short* __restrict__ Wb,
    int Kin, int Kpad, int N, int k0, int n0, unsigned short* tile /* [32][33] */) {
  const int tx = threadIdx.x & 31, ty = threadIdx.x >> 5; // ty 0..7
#pragma unroll
  for (int i = 0; i < 32; i += 8) {
    const int k = k0 + ty + i;
    tile[(ty + i) * 33 + tx] = (k < Kin) ? f2bf(W[(size_t)k * N + n0 + tx]) : (unsigned short)0;
  }
  __syncthreads();
#pragma unroll
  for (int i = 0; i < 32; i += 8)
    Wb[(size_t)(n0 + ty + i) * Kpad + k0 + tx] = tile[tx * 33 + ty + i];
}

// ---- fused prep: pack_x (3-segment, grid-stride) + transposes + qoff ----
__global__ __launch_bounds__(256) void prep_k(
    const float* __restrict__ state, const float* __restrict__ action,
    const float* __restrict__ W1, const float* __restrict__ W2,
    const float* __restrict__ Wq1, const float* __restrict__ bq1,
    const float* __restrict__ Wq2, const float* __restrict__ bq2,
    const float* __restrict__ Wh, const float* __restrict__ bh,
    unsigned short* __restrict__ xb, unsigned short* __restrict__ w1b,
    unsigned short* __restrict__ w2b, float* __restrict__ qoff) {
  __shared__ unsigned short tile[32 * 33];
  const int b = blockIdx.x;
  if (b < EW_BLOCKS) {
    // grid-stride over 8-element items; waves never straddle segments.
    for (int i = b * 256 + (int)threadIdx.x; i < EW_ITEMS; i += EW_BLOCKS * 256) {
      if (i < SEG0_ITEMS) {
        // state: row = i>>6, col = (i&63)*8; wave reads 2KB / writes 1KB contiguous
        const int r = i >> 6, c = (i & 63) << 3;
        const float* sp = state + (size_t)r * SDIM + c;
        float4 a = *(const float4*)sp;
        float4 bb = *(const float4*)(sp + 4);
        unsigned short* yp = xb + (size_t)r * KPAD1 + c;
        *(ushort4*)yp = cvt8lo(a);
        *(ushort4*)(yp + 4) = cvt8lo(bb);
      } else if (i < SEG0_ITEMS + SEG1_ITEMS) {
        const int j = i - SEG0_ITEMS;
        const int r = j >> 3, ca = (j & 7) << 3;  // col within action
        const float* ap = action + (size_t)r * ADIM + ca;
        float4 a = *(const float4*)ap;
        float4 bb = *(const float4*)(ap + 4);
        unsigned short* yp = xb + (size_t)r * KPAD1 + SDIM + ca;
        *(ushort4*)yp = cvt8lo(a);
        *(ushort4*)(yp + 4) = cvt8lo(bb);
      } else {
        const int j = i - SEG0_ITEMS - SEG1_ITEMS;
        const int r = j >> 3, cz = (j & 7) << 3;
        unsigned short* yp = xb + (size_t)r * KPAD1 + KDIM + cz;
        ushort4 z = {0, 0, 0, 0};
        *(ushort4*)yp = z;
        *(ushort4*)(yp + 4) = z;
      }
    }
  } else if (b < EW_BLOCKS + T1_BLOCKS) {
    const int t = b - EW_BLOCKS;
    transpose_body(W1, w1b, KDIM, KPAD1, HID, (t / 32) * 32, (t % 32) * 32, tile);
  } else if (b < EW_BLOCKS + T1_BLOCKS + T2_BLOCKS) {
    const int t = b - EW_BLOCKS - T1_BLOCKS;
    transpose_body(W2, w2b, HID, HID, HID, (t / 32) * 32, (t % 32) * 32, tile);
  } else {
    // qoff[q] = (te @ Wt)[q] + bh  (64 threads active)
    const int q = threadIdx.x;
    if (q < NQ) {
      const float tau = ((float)q + 0.5f) * (1.0f / (float)NQ);
      float t1[64];
#pragma unroll
      for (int k = 0; k < 64; ++k) t1[k] = fmaxf(fmaf(tau, Wq1[k], bq1[k]), 0.f);
      float acc = bh[0];
#pragma unroll 1
      for (int j = 0; j < 64; ++j) {
        float t2 = bq2[j];
#pragma unroll
        for (int k = 0; k < 64; ++k) t2 = fmaf(t1[k], Wq2[k * 64 + j], t2);
        acc = fmaf(t2, Wh[HID + j], acc);
      }
      qoff[q] = acc;
    }
  }
}

// ============================================================================
// 256x256 8-phase bf16 GEMM (round-2 configuration, best measured):
// C = bf16(A @ Bt^T + bias).  A: [M][K] bf16, Bt: [N][K] bf16, K % 128 == 0.
// 512 threads = 8 waves (2M x 4N), per-wave output 128x64.
// LDS 128 KiB: A[d][h] at d*32768+h*16384, B[d][h] at 65536 + same.
// st_16x32 swizzle (m201's): byte ^= ((byte>>9)&1)<<5, inverse on global src.
// vmcnt(4) at P4/P8; lgkmcnt(8) partial drain in 12-read phases.
// ============================================================================
__global__ __launch_bounds__(512, 2) void gemm8_k(
    const unsigned short* __restrict__ A, const unsigned short* __restrict__ Bt,
    const float* __restrict__ bias, unsigned short* __restrict__ C,
    int N, int K, int NT) {
  extern __shared__ unsigned short sm[];
  const int tid = threadIdx.x;
  const int w = tid >> 6, l = tid & 63;

  // bijective XCD chunk swizzle (gridDim.x % 8 == 0)
  const int cpx = (int)gridDim.x >> 3;
  int bid = (int)blockIdx.x;
  bid = (bid & 7) * cpx + (bid >> 3);
  const int nb = N >> 8;
  const int m0 = (bid / nb) << 8, n0 = (bid % nb) << 8;

  // staging mapping: lane covers linear LDS slot (w*1024 + l*16) within half;
  // row = i*64 + w*8 + (l>>3), col bytes = (l&7)*16, inverse-swizzled source.
  const int srow0 = w * 8 + (l >> 3);
  const int sce = ((((l & 7) << 4) ^ ((srow0 & 4) << 3)) >> 1);

  // fragment-read constants (byte offsets)
  const int aB = (w >> 2) * 16384;                 // A slot = wave's M-half
  const int bB = 65536 + ((w & 3) >> 1) * 16384;   // B slot = wave's N-half
  const int lr = (l & 15) << 7;                    // row-within-slot * 128B
  const int bRow = (w & 1) << 13;                  // (w&1)*64 rows * 128B
  const int cSw = (((l >> 4) << 4) ^ ((l & 4) << 3)); // swizzled col bytes

  f32x4 acc[8][4] = {};
  bf16x8 ra[2][4], rb[2][4];

#define AF(d, mi, kk) (*(const bf16x8*)(sm + ((aB + (d)*32768 + (mi)*2048 + lr + cSw + ((kk) << 6)) >> 1)))
#define BFR(d, ni, kk) (*(const bf16x8*)(sm + ((bB + (d)*32768 + bRow + (ni)*2048 + lr + cSw + ((kk) << 6)) >> 1)))
#define STGA(d, h, kt) do { \
    const unsigned short* g_ = A + (size_t)(m0 + (h)*128 + srow0) * K + (kt) + sce; \
    unsigned short* l_ = sm + (((d)*32768 + (h)*16384 + w*1024) >> 1); \
    gload_lds16(g_, l_); gload_lds16(g_ + (size_t)64 * K, l_ + 4096); } while (0)
#define STGB(d, h, kt) do { \
    const unsigned short* g_ = Bt + (size_t)(n0 + (h)*128 + srow0) * K + (kt) + sce; \
    unsigned short* l_ = sm + ((65536 + (d)*32768 + (h)*16384 + w*1024) >> 1); \
    gload_lds16(g_, l_); gload_lds16(g_ + (size_t)64 * K, l_ + 4096); } while (0)
#define RDA(d, base) do { _Pragma("unroll") for (int kk = 0; kk < 2; ++kk) \
    _Pragma("unroll") for (int mi = 0; mi < 4; ++mi) ra[kk][mi] = AF(d, (base) + mi, kk); } while (0)
#define RDB(d, base) do { _Pragma("unroll") for (int kk = 0; kk < 2; ++kk) \
    _Pragma("unroll") for (int ni = 0; ni < 2; ++ni) rb[kk][(base) + ni] = BFR(d, (base) + ni, kk); } while (0)
#define MQ(MO, NO) do { _Pragma("unroll") for (int kk = 0; kk < 2; ++kk) \
    _Pragma("unroll") for (int mi = 0; mi < 4; ++mi) \
    _Pragma("unroll") for (int ni = 0; ni < 2; ++ni) \
      acc[(MO) + mi][(NO) + ni] = __builtin_amdgcn_mfma_f32_16x16x32_bf16( \
          ra[kk][mi], rb[kk][(NO) + ni], acc[(MO) + mi][(NO) + ni], 0, 0, 0); } while (0)
#define BAR() __builtin_amdgcn_s_barrier()
#define WAITLGKM() asm volatile("s_waitcnt lgkmcnt(0)" ::: "memory")
#define WAITLGKM8() asm volatile("s_waitcnt lgkmcnt(8)" ::: "memory")
#define WAITVM(n) asm volatile("s_waitcnt vmcnt(" #n ")" ::: "memory")

  // prologue: tile0 fully + tile1 B-halves (12 loads); wait tile0 (leave 4)
  STGA(0, 0, 0); STGA(0, 1, 0); STGB(0, 0, 0); STGB(0, 1, 0);
  STGB(1, 0, 64); STGB(1, 1, 64);
  WAITVM(4); BAR();

  for (int t = 0; t < NT; t += 2) {
    const int kt1 = (t + 1) << 6;
    const int kt2 = ((t + 2 < NT) ? (t + 2) : (NT - 1)) << 6;
    const int kt3 = ((t + 3 < NT) ? (t + 3) : (NT - 1)) << 6;
    // P1: A(mh0)+B(nh0) reads, stage A[1][0]<-t+1, MFMA quad (0,0)
    RDA(0, 0); RDB(0, 0); STGA(1, 0, kt1);
    WAITLGKM8();
    BAR(); WAITLGKM();
    __builtin_amdgcn_s_setprio(1); MQ(0, 0); __builtin_amdgcn_s_setprio(0);
    BAR();
    // P2: B(nh1) reads, stage A[1][1]<-t+1, MFMA (0,2)
    RDB(0, 2); STGA(1, 1, kt1);
    BAR(); WAITLGKM();
    __builtin_amdgcn_s_setprio(1); MQ(0, 2); __builtin_amdgcn_s_setprio(0);
    BAR();
    // P3: A(mh1) reads, stage B[0][0]<-t+2 (B[0] last read in P2), MFMA (4,2)
    RDA(0, 4); STGB(0, 0, kt2);
    BAR(); WAITLGKM();
    __builtin_amdgcn_s_setprio(1); MQ(4, 2); __builtin_amdgcn_s_setprio(0);
    BAR();
    // P4: stage B[0][1]<-t+2, MFMA (4,0); counted wait: tile t+1 landed
    STGB(0, 1, kt2);
    BAR();
    __builtin_amdgcn_s_setprio(1); MQ(4, 0); __builtin_amdgcn_s_setprio(0);
    WAITVM(4); BAR();
    // P5: buf1 A(mh0)+B(nh0), stage A[0][0]<-t+2 (A[0] last read in P3), MFMA (0,0)
    RDA(1, 0); RDB(1, 0); STGA(0, 0, kt2);
    WAITLGKM8();
    BAR(); WAITLGKM();
    __builtin_amdgcn_s_setprio(1); MQ(0, 0); __builtin_amdgcn_s_setprio(0);
    BAR();
    // P6: B(nh1), stage A[0][1]<-t+2, MFMA (0,2)
    RDB(1, 2); STGA(0, 1, kt2);
    BAR(); WAITLGKM();
    __builtin_amdgcn_s_setprio(1); MQ(0, 2); __builtin_amdgcn_s_setprio(0);
    BAR();
    // P7: A(mh1), stage B[1][0]<-t+3 (B[1] last read in P6), MFMA (4,2)
    RDA(1, 4); STGB(1, 0, kt3);
    BAR(); WAITLGKM();
    __builtin_amdgcn_s_setprio(1); MQ(4, 2); __builtin_amdgcn_s_setprio(0);
    BAR();
    // P8: stage B[1][1]<-t+3, MFMA (4,0); counted wait: tile t+2 landed
    STGB(1, 1, kt3);
    BAR();
    __builtin_amdgcn_s_setprio(1); MQ(4, 0); __builtin_amdgcn_s_setprio(0);
    WAITVM(4); BAR();
  }

  // epilogue: drain staging queue, then C = bf16(acc + bias[col])
  WAITVM(0);
  const int wr = (w >> 2) << 7, wc = (w & 3) << 6;
#pragma unroll
  for (int mi = 0; mi < 8; ++mi) {
    const int row = m0 + wr + mi * 16 + ((l >> 4) << 2);
#pragma unroll
    for (int ni = 0; ni < 4; ++ni) {
      const int col = n0 + wc + ni * 16 + (l & 15);
      const float bc = bias[col];
#pragma unroll
      for (int r = 0; r < 4; ++r)
        C[(size_t)(row + r) * N + col] = f2bf(acc[mi][ni][r] + bc);
    }
  }
#undef AF
#undef BFR
#undef STGA
#undef STGB
#undef RDA
#undef RDB
#undef MQ
#undef BAR
#undef WAITLGKM
#undef WAITLGKM8
#undef WAITVM
}

// ---- LayerNorm + ReLU -> bf16, one wave per row of 1024 ----
__global__ __launch_bounds__(256) void ln_relu_k(
    const unsigned short* __restrict__ X, const float* __restrict__ g,
    const float* __restrict__ be, unsigned short* __restrict__ Y) {
  const int w = threadIdx.x >> 6, l = threadIdx.x & 63;
  const size_t row = (size_t)blockIdx.x * 4 + w;
  const unsigned short* xr = X + row * HID;
  float v[16];
  float sum = 0.f, ss = 0.f;
#pragma unroll
  for (int c = 0; c < 4; ++c) {
    ushort4 u = *(const ushort4*)(xr + (c * 64 + l) * 4);
    float a0 = bf2f(u.x), a1 = bf2f(u.y), a2 = bf2f(u.z), a3 = bf2f(u.w);
    v[c * 4 + 0] = a0; v[c * 4 + 1] = a1; v[c * 4 + 2] = a2; v[c * 4 + 3] = a3;
    sum += a0 + a1 + a2 + a3;
    ss += a0 * a0 + a1 * a1 + a2 * a2 + a3 * a3;
  }
#pragma unroll
  for (int o = 32; o > 0; o >>= 1) {
    sum += __shfl_xor(sum, o, 64);
    ss  += __shfl_xor(ss, o, 64);
  }
  const float mu = sum * (1.f / HID);
  const float rs = rsqrtf(ss * (1.f / HID) - mu * mu + 1e-5f);
  unsigned short* yr = Y + row * HID;
#pragma unroll
  for (int c = 0; c < 4; ++c) {
    const int col = (c * 64 + l) * 4;
    float4 gg = *(const float4*)(g + col);
    float4 bb = *(const float4*)(be + col);
    ushort4 o4;
    o4.x = f2bf(fmaxf((v[c * 4 + 0] - mu) * rs * gg.x + bb.x, 0.f));
    o4.y = f2bf(fmaxf((v[c * 4 + 1] - mu) * rs * gg.y + bb.y, 0.f));
    o4.z = f2bf(fmaxf((v[c * 4 + 2] - mu) * rs * gg.z + bb.z, 0.f));
    o4.w = f2bf(fmaxf((v[c * 4 + 3] - mu) * rs * gg.w + bb.w, 0.f));
    *(ushort4*)(yr + col) = o4;
  }
}

// ---- LN2 + ReLU + dot(row, Wf) + qoff broadcast -> out [B_ROWS][NQ] f32 ----
__global__ __launch_bounds__(256) void ln_final_k(
    const unsigned short* __restrict__ X, const float* __restrict__ g,
    const float* __restrict__ be, const float* __restrict__ Wh,
    const float* __restrict__ qoff, float* __restrict__ out) {
  const int w = threadIdx.x >> 6, l = threadIdx.x & 63;
  const size_t row = (size_t)blockIdx.x * 4 + w;
  const unsigned short* xr = X + row * HID;
  float v[16];
  float sum = 0.f, ss = 0.f;
#pragma unroll
  for (int c = 0; c < 4; ++c) {
    ushort4 u = *(const ushort4*)(xr + (c * 64 + l) * 4);
    float a0 = bf2f(u.x), a1 = bf2f(u.y), a2 = bf2f(u.z), a3 = bf2f(u.w);
    v[c * 4 + 0] = a0; v[c * 4 + 1] = a1; v[c * 4 + 2] = a2; v[c * 4 + 3] = a3;
    sum += a0 + a1 + a2 + a3;
    ss += a0 * a0 + a1 * a1 + a2 * a2 + a3 * a3;
  }
#pragma unroll
  for (int o = 32; o > 0; o >>= 1) {
    sum += __shfl_xor(sum, o, 64);
    ss  += __shfl_xor(ss, o, 64);
  }
  const float mu = sum * (1.f / HID);
  const float rs = rsqrtf(ss * (1.f / HID) - mu * mu + 1e-5f);
  float dot = 0.f;
#pragma unroll
  for (int c = 0; c < 4; ++c) {
    const int col = (c * 64 + l) * 4;
    float4 gg = *(const float4*)(g + col);
    float4 bb = *(const float4*)(be + col);
    float4 wf = *(const float4*)(Wh + col); // Wf = Wh[:HID]
    dot += fmaxf((v[c * 4 + 0] - mu) * rs * gg.x + bb.x, 0.f) * wf.x;
    dot += fmaxf((v[c * 4 + 1] - mu) * rs * gg.y + bb.y, 0.f) * wf.y;
    dot += fmaxf((v[c * 4 + 2] - mu) * rs * gg.z + bb.z, 0.f) * wf.z;
    dot += fmaxf((v[c * 4 + 3] - mu) * rs * gg.w + bb.w, 0.f) * wf.w;
  }
#pragma unroll
  for (int o = 32; o > 0; o >>= 1) dot += __shfl_xor(dot, o, 64);
  out[row * NQ + l] = dot + qoff[l];
}

extern "C" void kernel_launch(void* const* d_in, const int* in_sizes, int n_in,
                              void* d_out, int out_size, void* d_ws, size_t ws_size,
                              hipStream_t stream) {
  const float* state  = (const float*)d_in[0];
  const float* action = (const float*)d_in[1];
  const float* W1  = (const float*)d_in[2];
  const float* b1  = (const float*)d_in[3];
  const float* g1  = (const float*)d_in[4];
  const float* be1 = (const float*)d_in[5];
  const float* W2  = (const float*)d_in[6];
  const float* b2  = (const float*)d_in[7];
  const float* g2  = (const float*)d_in[8];
  const float* be2 = (const float*)d_in[9];
  const float* Wq1 = (const float*)d_in[10];
  const float* bq1 = (const float*)d_in[11];
  const float* Wq2 = (const float*)d_in[12];
  const float* bq2 = (const float*)d_in[13];
  const float* Wh  = (const float*)d_in[14];
  const float* bh  = (const float*)d_in[15];
  float* out = (float*)d_out;

  // workspace layout (~91.5 MB)
  char* ws = (char*)d_ws;
  size_t off = 0;
  float* qoff = (float*)(ws + off); off += 256;
  unsigned short* xb  = (unsigned short*)(ws + off); off += (size_t)B_ROWS * KPAD1 * 2; // 20.97 MB
  unsigned short* w1b = (unsigned short*)(ws + off); off += (size_t)HID * KPAD1 * 2;    // 1.31 MB
  unsigned short* w2b = (unsigned short*)(ws + off); off += (size_t)HID * HID * 2;      // 2.10 MB
  unsigned short* h1b = (unsigned short*)(ws + off); off += (size_t)B_ROWS * HID * 2;   // 33.55 MB
  unsigned short* tb  = (unsigned short*)(ws + off);                                    // 33.55 MB

  hipFuncSetAttribute((const void*)gemm8_k, hipFuncAttributeMaxDynamicSharedMemorySize, 131072);

  prep_k<<<PREP_BLOCKS, 256, 0, stream>>>(state, action, W1, W2, Wq1, bq1, Wq2, bq2,
                                          Wh, bh, xb, w1b, w2b, qoff);

  gemm8_k<<<(B_ROWS / 256) * (HID / 256), 512, 131072, stream>>>(xb, w1b, b1, tb, HID, KPAD1, KPAD1 / 64);
  ln_relu_k<<<B_ROWS / 4, 256, 0, stream>>>(tb, g1, be1, h1b);
  gemm8_k<<<(B_ROWS / 256) * (HID / 256), 512, 131072, stream>>>(h1b, w2b, b2, tb, HID, HID, HID / 64);
  ln_final_k<<<B_ROWS / 4, 256, 0, stream>>>(tb, g2, be2, Wh, qoff, out);
}